// Round 3
// baseline (212.262 us; speedup 1.0000x reference)
//
#include <hip/hip_runtime.h>

#define D_MODEL 1024
#define T_SEQ   512
#define B_BATCH 64
#define ROWS_PER_BLOCK 16

// ---------------------------------------------------------------------------
// Phase 1: per-batch-row scan over T=512 (int32 inputs).
//   inc      = rel > 0
//   c        = exclusive cumsum(inc)
//   reset    = (rel==0 && prev_rel>0)
//   baseline = inclusive cummax(reset ? c : 0)
//   cp       = c - baseline
//   role     = id<=4 ? 3 : (rel==0 ? 2 : 0)
// One block of 512 threads per batch row; Hillis-Steele scans in LDS.
// Output packed cp | (role<<16) into workspace.
// ---------------------------------------------------------------------------
__global__ __launch_bounds__(512) void gpe_scan_kernel(
    const int* __restrict__ input_ids,
    const int* __restrict__ rel_ids,
    int* __restrict__ cp_role)
{
    __shared__ int s[T_SEQ];
    __shared__ int srel[T_SEQ];

    const int b = blockIdx.x;
    const int t = threadIdx.x;
    const int idx = b * T_SEQ + t;

    const int rel = rel_ids[idx];
    const int id  = input_ids[idx];
    srel[t] = rel;

    const int inc = (rel > 0) ? 1 : 0;
    int v = inc;
    s[t] = v;
    __syncthreads();

    // inclusive prefix sum (Hillis-Steele)
    for (int off = 1; off < T_SEQ; off <<= 1) {
        int add = (t >= off) ? s[t - off] : 0;
        __syncthreads();
        v += add;
        s[t] = v;
        __syncthreads();
    }
    const int c = v - inc;  // exclusive cumsum

    const int prev_rel = (t == 0) ? 0 : srel[t - 1];
    const int reset = (rel == 0 && prev_rel > 0);
    int m = reset ? c : 0;
    __syncthreads();
    s[t] = m;
    __syncthreads();

    // inclusive prefix max
    for (int off = 1; off < T_SEQ; off <<= 1) {
        int other = (t >= off) ? s[t - off] : 0;
        __syncthreads();
        m = max(m, other);
        s[t] = m;
        __syncthreads();
    }

    const int cp   = c - m;
    const int role = (id <= 4) ? 3 : ((rel == 0) ? 2 : 0);
    cp_role[idx] = cp | (role << 16);
}

// ---------------------------------------------------------------------------
// Phase 2: out[b,t,d] = seq[t,d] + 0.5*chain[cp,d] + 0.3*depth[0,d]
//                       + 0.2*role_table[role,d]
// Tables are FLOAT32; output is FLOAT32.
// Block = 128 threads; thread i owns d = i*8..i*8+7. Block processes
// ROWS_PER_BLOCK consecutive rows; per-thread preload of
// 0.3*depth[0] + 0.2*role[r] (r=0..3) amortized across the strip.
// ---------------------------------------------------------------------------
__global__ __launch_bounds__(128) void gpe_emb_kernel(
    const float* __restrict__ seq_table,    // [512,1024] f32
    const float* __restrict__ chain_table,  // [1000,1024] f32
    const float* __restrict__ depth_table,  // [20,1024] f32
    const float* __restrict__ role_table,   // [4,1024] f32
    const int* __restrict__ cp_role,        // [B*T] packed cp|role<<16
    float* __restrict__ out)                // [B,T,1024] f32
{
    const int d0   = threadIdx.x << 3;              // 0..1016, step 8
    const int row0 = blockIdx.x * ROWS_PER_BLOCK;

    // Preload per-thread constants: base[r][j] = 0.3*depth[0][d0+j] + 0.2*role[r][d0+j]
    float base[4][8];
    {
        const float4 da = *reinterpret_cast<const float4*>(depth_table + d0);
        const float4 db = *reinterpret_cast<const float4*>(depth_table + d0 + 4);
        const float dep[8] = {da.x, da.y, da.z, da.w, db.x, db.y, db.z, db.w};
#pragma unroll
        for (int r = 0; r < 4; ++r) {
            const float4 ra = *reinterpret_cast<const float4*>(role_table + r * D_MODEL + d0);
            const float4 rb = *reinterpret_cast<const float4*>(role_table + r * D_MODEL + d0 + 4);
            const float rv[8] = {ra.x, ra.y, ra.z, ra.w, rb.x, rb.y, rb.z, rb.w};
#pragma unroll
            for (int j = 0; j < 8; ++j)
                base[r][j] = 0.3f * dep[j] + 0.2f * rv[j];
        }
    }

#pragma unroll 2
    for (int k = 0; k < ROWS_PER_BLOCK; ++k) {
        const int row = row0 + k;
        const int t   = row & (T_SEQ - 1);
        const int pr  = cp_role[row];
        const int cp   = pr & 0xffff;
        const int role = pr >> 16;

        const float4 sa = *reinterpret_cast<const float4*>(seq_table + t * D_MODEL + d0);
        const float4 sb = *reinterpret_cast<const float4*>(seq_table + t * D_MODEL + d0 + 4);
        const float4 ca = *reinterpret_cast<const float4*>(chain_table + cp * D_MODEL + d0);
        const float4 cb = *reinterpret_cast<const float4*>(chain_table + cp * D_MODEL + d0 + 4);

        const float sv[8] = {sa.x, sa.y, sa.z, sa.w, sb.x, sb.y, sb.z, sb.w};
        const float cv[8] = {ca.x, ca.y, ca.z, ca.w, cb.x, cb.y, cb.z, cb.w};

        float ov[8];
#pragma unroll
        for (int j = 0; j < 8; ++j)
            ov[j] = sv[j] + 0.5f * cv[j] + base[role][j];

        float4 ra, rb2;
        ra.x  = ov[0]; ra.y  = ov[1]; ra.z  = ov[2]; ra.w  = ov[3];
        rb2.x = ov[4]; rb2.y = ov[5]; rb2.z = ov[6]; rb2.w = ov[7];
        float* outp = out + row * D_MODEL + d0;
        *reinterpret_cast<float4*>(outp)     = ra;
        *reinterpret_cast<float4*>(outp + 4) = rb2;
    }
}

extern "C" void kernel_launch(void* const* d_in, const int* in_sizes, int n_in,
                              void* d_out, int out_size, void* d_ws, size_t ws_size,
                              hipStream_t stream) {
    const int* input_ids = (const int*)d_in[0];
    const int* rel_ids   = (const int*)d_in[1];
    const float* seq_table   = (const float*)d_in[2];
    const float* chain_table = (const float*)d_in[3];
    const float* depth_table = (const float*)d_in[4];
    const float* role_table  = (const float*)d_in[5];
    float* out = (float*)d_out;

    int* cp_role = (int*)d_ws;  // B*T ints = 128 KB

    gpe_scan_kernel<<<B_BATCH, T_SEQ, 0, stream>>>(input_ids, rel_ids, cp_role);

    const int n_rows = B_BATCH * T_SEQ;  // 32768
    gpe_emb_kernel<<<n_rows / ROWS_PER_BLOCK, 128, 0, stream>>>(
        seq_table, chain_table, depth_table, role_table, cp_role, out);
}

// Round 5
// 185.783 us; speedup vs baseline: 1.1425x; 1.1425x over previous
//
#include <hip/hip_runtime.h>

#define D_MODEL 1024
#define T_SEQ   512
#define B_BATCH 64
#define ROWS_PER_BLOCK 8

typedef float nt_f4 __attribute__((ext_vector_type(4)));

// ---------------------------------------------------------------------------
// Phase 1: per-batch-row scan over T=512, one WAVE (64 lanes) per row.
// Each lane owns 8 consecutive t. Local serial scan + wave shuffle scan.
// No LDS, no barriers.
//   inc      = rel > 0
//   c        = exclusive cumsum(inc)
//   reset    = (rel==0 && prev_rel>0)
//   baseline = inclusive cummax(reset ? c : 0)
//   cp       = c - baseline
//   role     = id<=4 ? 3 : (rel==0 ? 2 : 0)
// Output packed cp | (role<<16) into workspace.
// ---------------------------------------------------------------------------
__global__ __launch_bounds__(64) void gpe_scan_kernel(
    const int* __restrict__ input_ids,
    const int* __restrict__ rel_ids,
    int* __restrict__ cp_role)
{
    const int b    = blockIdx.x;
    const int lane = threadIdx.x;            // 0..63
    const int base = b * T_SEQ + lane * 8;

    const int4 ra = *reinterpret_cast<const int4*>(rel_ids + base);
    const int4 rb = *reinterpret_cast<const int4*>(rel_ids + base + 4);
    const int4 ia = *reinterpret_cast<const int4*>(input_ids + base);
    const int4 ib = *reinterpret_cast<const int4*>(input_ids + base + 4);
    const int rel[8] = {ra.x, ra.y, ra.z, ra.w, rb.x, rb.y, rb.z, rb.w};
    const int id[8]  = {ia.x, ia.y, ia.z, ia.w, ib.x, ib.y, ib.z, ib.w};

    // local exclusive cumsum of inc
    int cl[8];
    int run = 0;
#pragma unroll
    for (int j = 0; j < 8; ++j) { cl[j] = run; run += (rel[j] > 0) ? 1 : 0; }

    // wave inclusive prefix sum of per-lane totals -> exclusive
    int incl = run;
#pragma unroll
    for (int off = 1; off < 64; off <<= 1) {
        const int n = __shfl_up(incl, off);
        if (lane >= off) incl += n;
    }
    const int excl = incl - run;

    int c[8];
#pragma unroll
    for (int j = 0; j < 8; ++j) c[j] = excl + cl[j];

    // prev_rel for j==0 comes from previous lane's rel[7]
    int prev0 = __shfl_up(rel[7], 1);
    if (lane == 0) prev0 = 0;

    // local inclusive cummax of (reset ? c : 0)
    int ml[8];
    int mrun = 0;
#pragma unroll
    for (int j = 0; j < 8; ++j) {
        const int prl  = (j == 0) ? prev0 : rel[j - 1];
        const int mask = (rel[j] == 0 && prl > 0) ? c[j] : 0;
        mrun = max(mrun, mask);
        ml[j] = mrun;
    }

    // wave inclusive prefix max of per-lane maxima -> exclusive
    int minc = mrun;
#pragma unroll
    for (int off = 1; off < 64; off <<= 1) {
        const int n = __shfl_up(minc, off);
        if (lane >= off) minc = max(minc, n);
    }
    int mexcl = __shfl_up(minc, 1);
    if (lane == 0) mexcl = 0;

    int outp[8];
#pragma unroll
    for (int j = 0; j < 8; ++j) {
        const int m    = max(mexcl, ml[j]);
        const int cp   = c[j] - m;
        const int role = (id[j] <= 4) ? 3 : ((rel[j] == 0) ? 2 : 0);
        outp[j] = cp | (role << 16);
    }
    *reinterpret_cast<int4*>(cp_role + base)     = make_int4(outp[0], outp[1], outp[2], outp[3]);
    *reinterpret_cast<int4*>(cp_role + base + 4) = make_int4(outp[4], outp[5], outp[6], outp[7]);
}

// ---------------------------------------------------------------------------
// Phase 2: out[b,t,d] = seq[t,d] + 0.5*chain[cp,d] + 0.3*depth[0,d]
//                       + 0.2*role_table[role,d]          (all f32)
// Block = 256 threads; thread owns 8 d-columns of one of 2 interleaved rows;
// 8 rows per block (4 fully-unrolled iterations). cp_role prefetched.
// Nontemporal stores: output is write-once streaming — keep L2 for tables.
// ---------------------------------------------------------------------------
__global__ __launch_bounds__(256) void gpe_emb_kernel(
    const float* __restrict__ seq_table,    // [512,1024]
    const float* __restrict__ chain_table,  // [1000,1024]
    const float* __restrict__ depth_table,  // [20,1024]
    const float* __restrict__ role_table,   // [4,1024]
    const int* __restrict__ cp_role,        // [B*T] packed cp|role<<16
    float* __restrict__ out)                // [B,T,1024]
{
    const int tid  = threadIdx.x;
    const int d0   = (tid & 127) << 3;      // 0..1016, step 8
    const int rsub = tid >> 7;              // 0 or 1
    const int row0 = blockIdx.x * ROWS_PER_BLOCK + rsub;

    // Prefetch packed cp|role for all 4 rows this thread touches.
    int pr[4];
#pragma unroll
    for (int k = 0; k < 4; ++k) pr[k] = cp_role[row0 + 2 * k];

    // Preload per-thread constants: base[r][j] = 0.3*depth[0][d0+j] + 0.2*role[r][d0+j]
    float base[4][8];
    {
        const float4 da = *reinterpret_cast<const float4*>(depth_table + d0);
        const float4 db = *reinterpret_cast<const float4*>(depth_table + d0 + 4);
        const float dep[8] = {da.x, da.y, da.z, da.w, db.x, db.y, db.z, db.w};
#pragma unroll
        for (int r = 0; r < 4; ++r) {
            const float4 ta = *reinterpret_cast<const float4*>(role_table + r * D_MODEL + d0);
            const float4 tb = *reinterpret_cast<const float4*>(role_table + r * D_MODEL + d0 + 4);
            const float rv[8] = {ta.x, ta.y, ta.z, ta.w, tb.x, tb.y, tb.z, tb.w};
#pragma unroll
            for (int j = 0; j < 8; ++j)
                base[r][j] = 0.3f * dep[j] + 0.2f * rv[j];
        }
    }

#pragma unroll
    for (int k = 0; k < 4; ++k) {
        const int row  = row0 + 2 * k;
        const int t    = row & (T_SEQ - 1);
        const int cp   = pr[k] & 0xffff;
        const int role = pr[k] >> 16;

        const float4 sa = *reinterpret_cast<const float4*>(seq_table + t * D_MODEL + d0);
        const float4 sb = *reinterpret_cast<const float4*>(seq_table + t * D_MODEL + d0 + 4);
        const float4 ca = *reinterpret_cast<const float4*>(chain_table + cp * D_MODEL + d0);
        const float4 cb = *reinterpret_cast<const float4*>(chain_table + cp * D_MODEL + d0 + 4);

        nt_f4 oa, ob;
        oa.x = sa.x + 0.5f * ca.x + base[role][0];
        oa.y = sa.y + 0.5f * ca.y + base[role][1];
        oa.z = sa.z + 0.5f * ca.z + base[role][2];
        oa.w = sa.w + 0.5f * ca.w + base[role][3];
        ob.x = sb.x + 0.5f * cb.x + base[role][4];
        ob.y = sb.y + 0.5f * cb.y + base[role][5];
        ob.z = sb.z + 0.5f * cb.z + base[role][6];
        ob.w = sb.w + 0.5f * cb.w + base[role][7];

        float* outp = out + row * D_MODEL + d0;
        __builtin_nontemporal_store(oa, reinterpret_cast<nt_f4*>(outp));
        __builtin_nontemporal_store(ob, reinterpret_cast<nt_f4*>(outp + 4));
    }
}

extern "C" void kernel_launch(void* const* d_in, const int* in_sizes, int n_in,
                              void* d_out, int out_size, void* d_ws, size_t ws_size,
                              hipStream_t stream) {
    const int* input_ids = (const int*)d_in[0];
    const int* rel_ids   = (const int*)d_in[1];
    const float* seq_table   = (const float*)d_in[2];
    const float* chain_table = (const float*)d_in[3];
    const float* depth_table = (const float*)d_in[4];
    const float* role_table  = (const float*)d_in[5];
    float* out = (float*)d_out;

    int* cp_role = (int*)d_ws;  // B*T ints = 128 KB

    gpe_scan_kernel<<<B_BATCH, 64, 0, stream>>>(input_ids, rel_ids, cp_role);

    const int n_rows = B_BATCH * T_SEQ;  // 32768
    gpe_emb_kernel<<<n_rows / ROWS_PER_BLOCK, 256, 0, stream>>>(
        seq_table, chain_table, depth_table, role_table, cp_role, out);
}

// Round 6
// 168.663 us; speedup vs baseline: 1.2585x; 1.1015x over previous
//
#include <hip/hip_runtime.h>

#define D_MODEL 1024
#define T_SEQ   512
#define B_BATCH 64
#define ROWS_PER_BLOCK 8

// ---------------------------------------------------------------------------
// Phase 1: per-batch-row scan over T=512, one WAVE (64 lanes) per row.
// Each lane owns 8 consecutive t. Local serial scan + wave shuffle scan.
// No LDS, no barriers.
// ---------------------------------------------------------------------------
__global__ __launch_bounds__(64) void gpe_scan_kernel(
    const int* __restrict__ input_ids,
    const int* __restrict__ rel_ids,
    int* __restrict__ cp_role)
{
    const int b    = blockIdx.x;
    const int lane = threadIdx.x;            // 0..63
    const int base = b * T_SEQ + lane * 8;

    const int4 ra = *reinterpret_cast<const int4*>(rel_ids + base);
    const int4 rb = *reinterpret_cast<const int4*>(rel_ids + base + 4);
    const int4 ia = *reinterpret_cast<const int4*>(input_ids + base);
    const int4 ib = *reinterpret_cast<const int4*>(input_ids + base + 4);
    const int rel[8] = {ra.x, ra.y, ra.z, ra.w, rb.x, rb.y, rb.z, rb.w};
    const int id[8]  = {ia.x, ia.y, ia.z, ia.w, ib.x, ib.y, ib.z, ib.w};

    // local exclusive cumsum of inc
    int cl[8];
    int run = 0;
#pragma unroll
    for (int j = 0; j < 8; ++j) { cl[j] = run; run += (rel[j] > 0) ? 1 : 0; }

    // wave inclusive prefix sum of per-lane totals -> exclusive
    int incl = run;
#pragma unroll
    for (int off = 1; off < 64; off <<= 1) {
        const int n = __shfl_up(incl, off);
        if (lane >= off) incl += n;
    }
    const int excl = incl - run;

    int c[8];
#pragma unroll
    for (int j = 0; j < 8; ++j) c[j] = excl + cl[j];

    // prev_rel for j==0 comes from previous lane's rel[7]
    int prev0 = __shfl_up(rel[7], 1);
    if (lane == 0) prev0 = 0;

    // local inclusive cummax of (reset ? c : 0)
    int ml[8];
    int mrun = 0;
#pragma unroll
    for (int j = 0; j < 8; ++j) {
        const int prl  = (j == 0) ? prev0 : rel[j - 1];
        const int mask = (rel[j] == 0 && prl > 0) ? c[j] : 0;
        mrun = max(mrun, mask);
        ml[j] = mrun;
    }

    // wave inclusive prefix max of per-lane maxima -> exclusive
    int minc = mrun;
#pragma unroll
    for (int off = 1; off < 64; off <<= 1) {
        const int n = __shfl_up(minc, off);
        if (lane >= off) minc = max(minc, n);
    }
    int mexcl = __shfl_up(minc, 1);
    if (lane == 0) mexcl = 0;

    int outp[8];
#pragma unroll
    for (int j = 0; j < 8; ++j) {
        const int m    = max(mexcl, ml[j]);
        const int cp   = c[j] - m;
        const int role = (id[j] <= 4) ? 3 : ((rel[j] == 0) ? 2 : 0);
        outp[j] = cp | (role << 16);
    }
    *reinterpret_cast<int4*>(cp_role + base)     = make_int4(outp[0], outp[1], outp[2], outp[3]);
    *reinterpret_cast<int4*>(cp_role + base + 4) = make_int4(outp[4], outp[5], outp[6], outp[7]);
}

// ---------------------------------------------------------------------------
// Phase 2: out[b,t,d] = seq[t,d] + 0.5*chain[cp,d] + 0.3*depth[0,d]
//                       + 0.2*role_table[role,d]          (all f32)
// fillBuffer-shaped access: 256 threads, thread owns ONE float4 (d0=tid*4)
// -> every load/store instruction is a fully-coalesced 1 KB per wave.
// Block processes 8 consecutive rows; cp_role index is block-uniform
// (scalar loads). base[r] = 0.3*depth+0.2*role[r] preloaded (16 VGPRs).
// ---------------------------------------------------------------------------
__global__ __launch_bounds__(256) void gpe_emb_kernel(
    const float* __restrict__ seq_table,    // [512,1024]
    const float* __restrict__ chain_table,  // [1000,1024]
    const float* __restrict__ depth_table,  // [20,1024]
    const float* __restrict__ role_table,   // [4,1024]
    const int* __restrict__ cp_role,        // [B*T] packed cp|role<<16
    float* __restrict__ out)                // [B,T,1024]
{
    const int d0   = threadIdx.x << 2;               // 0..1020, step 4
    const int row0 = blockIdx.x * ROWS_PER_BLOCK;

    // Prefetch packed cp|role for the block's 8 rows (uniform -> scalar regs).
    int pr[ROWS_PER_BLOCK];
#pragma unroll
    for (int k = 0; k < ROWS_PER_BLOCK; ++k) pr[k] = cp_role[row0 + k];

    // base[r] = 0.3*depth[0][d0..d0+3] + 0.2*role[r][d0..d0+3]
    float4 basev[4];
    {
        const float4 dep = *reinterpret_cast<const float4*>(depth_table + d0);
#pragma unroll
        for (int r = 0; r < 4; ++r) {
            const float4 rv = *reinterpret_cast<const float4*>(role_table + r * D_MODEL + d0);
            basev[r].x = 0.3f * dep.x + 0.2f * rv.x;
            basev[r].y = 0.3f * dep.y + 0.2f * rv.y;
            basev[r].z = 0.3f * dep.z + 0.2f * rv.z;
            basev[r].w = 0.3f * dep.w + 0.2f * rv.w;
        }
    }

#pragma unroll
    for (int k = 0; k < ROWS_PER_BLOCK; ++k) {
        const int row  = row0 + k;
        const int t    = row & (T_SEQ - 1);
        const int cp   = pr[k] & 0xffff;
        const int role = pr[k] >> 16;

        const float4 sv = *reinterpret_cast<const float4*>(seq_table   + t  * D_MODEL + d0);
        const float4 cv = *reinterpret_cast<const float4*>(chain_table + cp * D_MODEL + d0);
        const float4 bv = basev[role];

        float4 ov;
        ov.x = sv.x + 0.5f * cv.x + bv.x;
        ov.y = sv.y + 0.5f * cv.y + bv.y;
        ov.z = sv.z + 0.5f * cv.z + bv.z;
        ov.w = sv.w + 0.5f * cv.w + bv.w;

        *reinterpret_cast<float4*>(out + row * D_MODEL + d0) = ov;
    }
}

extern "C" void kernel_launch(void* const* d_in, const int* in_sizes, int n_in,
                              void* d_out, int out_size, void* d_ws, size_t ws_size,
                              hipStream_t stream) {
    const int* input_ids = (const int*)d_in[0];
    const int* rel_ids   = (const int*)d_in[1];
    const float* seq_table   = (const float*)d_in[2];
    const float* chain_table = (const float*)d_in[3];
    const float* depth_table = (const float*)d_in[4];
    const float* role_table  = (const float*)d_in[5];
    float* out = (float*)d_out;

    int* cp_role = (int*)d_ws;  // B*T ints = 128 KB

    gpe_scan_kernel<<<B_BATCH, 64, 0, stream>>>(input_ids, rel_ids, cp_role);

    const int n_rows = B_BATCH * T_SEQ;  // 32768
    gpe_emb_kernel<<<n_rows / ROWS_PER_BLOCK, 256, 0, stream>>>(
        seq_table, chain_table, depth_table, role_table, cp_role, out);
}

// Round 7
// 164.387 us; speedup vs baseline: 1.2912x; 1.0260x over previous
//
#include <hip/hip_runtime.h>

#define D_MODEL 1024
#define T_SEQ   512
#define B_BATCH 64
#define ROWS_PER_BLOCK 8

typedef float nt_f4 __attribute__((ext_vector_type(4)));

// ---------------------------------------------------------------------------
// Phase 1: per-batch-row scan over T=512, one WAVE (64 lanes) per row.
// Each lane owns 8 consecutive t. Local serial scan + wave shuffle scan.
// No LDS, no barriers.
// ---------------------------------------------------------------------------
__global__ __launch_bounds__(64) void gpe_scan_kernel(
    const int* __restrict__ input_ids,
    const int* __restrict__ rel_ids,
    int* __restrict__ cp_role)
{
    const int b    = blockIdx.x;
    const int lane = threadIdx.x;            // 0..63
    const int base = b * T_SEQ + lane * 8;

    const int4 ra = *reinterpret_cast<const int4*>(rel_ids + base);
    const int4 rb = *reinterpret_cast<const int4*>(rel_ids + base + 4);
    const int4 ia = *reinterpret_cast<const int4*>(input_ids + base);
    const int4 ib = *reinterpret_cast<const int4*>(input_ids + base + 4);
    const int rel[8] = {ra.x, ra.y, ra.z, ra.w, rb.x, rb.y, rb.z, rb.w};
    const int id[8]  = {ia.x, ia.y, ia.z, ia.w, ib.x, ib.y, ib.z, ib.w};

    // local exclusive cumsum of inc
    int cl[8];
    int run = 0;
#pragma unroll
    for (int j = 0; j < 8; ++j) { cl[j] = run; run += (rel[j] > 0) ? 1 : 0; }

    // wave inclusive prefix sum of per-lane totals -> exclusive
    int incl = run;
#pragma unroll
    for (int off = 1; off < 64; off <<= 1) {
        const int n = __shfl_up(incl, off);
        if (lane >= off) incl += n;
    }
    const int excl = incl - run;

    int c[8];
#pragma unroll
    for (int j = 0; j < 8; ++j) c[j] = excl + cl[j];

    // prev_rel for j==0 comes from previous lane's rel[7]
    int prev0 = __shfl_up(rel[7], 1);
    if (lane == 0) prev0 = 0;

    // local inclusive cummax of (reset ? c : 0)
    int ml[8];
    int mrun = 0;
#pragma unroll
    for (int j = 0; j < 8; ++j) {
        const int prl  = (j == 0) ? prev0 : rel[j - 1];
        const int mask = (rel[j] == 0 && prl > 0) ? c[j] : 0;
        mrun = max(mrun, mask);
        ml[j] = mrun;
    }

    // wave inclusive prefix max of per-lane maxima -> exclusive
    int minc = mrun;
#pragma unroll
    for (int off = 1; off < 64; off <<= 1) {
        const int n = __shfl_up(minc, off);
        if (lane >= off) minc = max(minc, n);
    }
    int mexcl = __shfl_up(minc, 1);
    if (lane == 0) mexcl = 0;

    int outp[8];
#pragma unroll
    for (int j = 0; j < 8; ++j) {
        const int m    = max(mexcl, ml[j]);
        const int cp   = c[j] - m;
        const int role = (id[j] <= 4) ? 3 : ((rel[j] == 0) ? 2 : 0);
        outp[j] = cp | (role << 16);
    }
    *reinterpret_cast<int4*>(cp_role + base)     = make_int4(outp[0], outp[1], outp[2], outp[3]);
    *reinterpret_cast<int4*>(cp_role + base + 4) = make_int4(outp[4], outp[5], outp[6], outp[7]);
}

// ---------------------------------------------------------------------------
// Phase 2: out[b,t,d] = seq[t,d] + 0.5*chain[cp,d] + 0.3*depth[0,d]
//                       + 0.2*role_table[role,d]          (all f32)
// fillBuffer-shaped access: 256 threads, thread owns ONE float4 (d0=tid*4)
// -> every load/store instruction is a fully-coalesced 1 KB per wave.
// Block processes 8 consecutive rows; cp_role index is block-uniform
// (scalar loads). base[r] = 0.3*depth+0.2*role[r] preloaded.
// NONTEMPORAL stores: the 131 MB output is write-once — bypass L2 so the
// seq/chain tables stay L2-resident and reads don't compete with the stream.
// ---------------------------------------------------------------------------
__global__ __launch_bounds__(256) void gpe_emb_kernel(
    const float* __restrict__ seq_table,    // [512,1024]
    const float* __restrict__ chain_table,  // [1000,1024]
    const float* __restrict__ depth_table,  // [20,1024]
    const float* __restrict__ role_table,   // [4,1024]
    const int* __restrict__ cp_role,        // [B*T] packed cp|role<<16
    float* __restrict__ out)                // [B,T,1024]
{
    const int d0   = threadIdx.x << 2;               // 0..1020, step 4
    const int row0 = blockIdx.x * ROWS_PER_BLOCK;

    // Prefetch packed cp|role for the block's 8 rows (uniform -> scalar regs).
    int pr[ROWS_PER_BLOCK];
#pragma unroll
    for (int k = 0; k < ROWS_PER_BLOCK; ++k) pr[k] = cp_role[row0 + k];

    // base[r] = 0.3*depth[0][d0..d0+3] + 0.2*role[r][d0..d0+3]
    float4 basev[4];
    {
        const float4 dep = *reinterpret_cast<const float4*>(depth_table + d0);
#pragma unroll
        for (int r = 0; r < 4; ++r) {
            const float4 rv = *reinterpret_cast<const float4*>(role_table + r * D_MODEL + d0);
            basev[r].x = 0.3f * dep.x + 0.2f * rv.x;
            basev[r].y = 0.3f * dep.y + 0.2f * rv.y;
            basev[r].z = 0.3f * dep.z + 0.2f * rv.z;
            basev[r].w = 0.3f * dep.w + 0.2f * rv.w;
        }
    }

#pragma unroll
    for (int k = 0; k < ROWS_PER_BLOCK; ++k) {
        const int row  = row0 + k;
        const int t    = row & (T_SEQ - 1);
        const int cp   = pr[k] & 0xffff;
        const int role = pr[k] >> 16;

        const float4 sv = *reinterpret_cast<const float4*>(seq_table   + t  * D_MODEL + d0);
        const float4 cv = *reinterpret_cast<const float4*>(chain_table + cp * D_MODEL + d0);
        const float4 bv = basev[role];

        nt_f4 ov;
        ov.x = sv.x + 0.5f * cv.x + bv.x;
        ov.y = sv.y + 0.5f * cv.y + bv.y;
        ov.z = sv.z + 0.5f * cv.z + bv.z;
        ov.w = sv.w + 0.5f * cv.w + bv.w;

        __builtin_nontemporal_store(ov, reinterpret_cast<nt_f4*>(out + row * D_MODEL + d0));
    }
}

extern "C" void kernel_launch(void* const* d_in, const int* in_sizes, int n_in,
                              void* d_out, int out_size, void* d_ws, size_t ws_size,
                              hipStream_t stream) {
    const int* input_ids = (const int*)d_in[0];
    const int* rel_ids   = (const int*)d_in[1];
    const float* seq_table   = (const float*)d_in[2];
    const float* chain_table = (const float*)d_in[3];
    const float* depth_table = (const float*)d_in[4];
    const float* role_table  = (const float*)d_in[5];
    float* out = (float*)d_out;

    int* cp_role = (int*)d_ws;  // B*T ints = 128 KB

    gpe_scan_kernel<<<B_BATCH, 64, 0, stream>>>(input_ids, rel_ids, cp_role);

    const int n_rows = B_BATCH * T_SEQ;  // 32768
    gpe_emb_kernel<<<n_rows / ROWS_PER_BLOCK, 256, 0, stream>>>(
        seq_table, chain_table, depth_table, role_table, cp_role, out);
}